// Round 13
// baseline (191.044 us; speedup 1.0000x reference)
//
#include <hip/hip_runtime.h>

// Downsampling_77214922047594 — B=4, N=8192, M=32768, K=16, C=128, G=8, f32 I/O
// Round 14: round-12 pipeline (passed, 190.9 µs best) + ONE change: k_head
// gather issues 2 explicit 8-deep float4 load batches per row (int4 indices,
// float4 IDW weights) to raise per-wave MLP at 8 blocks/CU occupancy.
// Distinguishes "per-wave MLP limited" vs "per-CU contention floor".

constexpr int NPB = 8192;            // N per batch
constexpr int BN  = 32768;           // total rows
constexpr int CH  = 128;
constexpr int KNB = 16;              // neighbors
constexpr int MS  = 32768;           // s_feats rows per batch
constexpr int NG  = 8;               // groups
constexpr int CG  = 16;              // channels per group
constexpr int MRPB = 16;             // rows per block (all passes)
constexpr int MNBLK = BN / MRPB;     // 2048 blocks
constexpr int MBPB  = NPB / MRPB;    // 512 blocks per batch
constexpr int XS = 152;              // LDS stride (shorts): 304B rows -> 2-way banks

typedef short short8 __attribute__((ext_vector_type(8)));
typedef float floatx4 __attribute__((ext_vector_type(4)));

static __device__ __forceinline__ unsigned short f2bs(float f) {
    unsigned int u = __builtin_bit_cast(unsigned int, f);
    unsigned int r = (u + 0x7fffu + ((u >> 16) & 1u)) >> 16;   // RNE
    return (unsigned short)r;
}
static __device__ __forceinline__ float bs2f(unsigned short s) {
    unsigned int u = ((unsigned int)s) << 16;
    return __builtin_bit_cast(float, u);
}

// ---------------- W prep: ALL layers fragment-major ----------------
// Wf[((j*4+kt)*64+lane)*8+e] = bf16(W[k][n]), n=j*16+lr, k=kt*32+qd*8+e,
// lane=qd*16+lr  => per (j,kt) a wave loads 1 KB contiguous.
__global__ __launch_bounds__(256) void k_prep(
    const float* __restrict__ W1, const float* __restrict__ W2,
    const float* __restrict__ W3,
    unsigned short* __restrict__ Wf1, unsigned short* __restrict__ Wf2,
    unsigned short* __restrict__ Wf3)
{
    const int bi = blockIdx.x;          // 0..191
    const int w  = bi >> 6;
    const int i  = bi & 63;
    const int el = i * 256 + threadIdx.x;
    const int n  = el >> 7, k = el & 127;
    const float* W = (w == 0) ? W1 : (w == 1) ? W2 : W3;
    unsigned short v = f2bs(W[k * 128 + n]);
    unsigned short* Wf = (w == 0) ? Wf1 : (w == 1) ? Wf2 : Wf3;
    int j = n >> 4, lr = n & 15;
    int kt = k >> 5, qd = (k >> 3) & 3, e = k & 7;
    Wf[(((j * 4 + kt) * 64) + (qd * 16 + lr)) * 8 + e] = v;
}

// ---------------- head: IDW gather + GEMM1, 16-row tiles, 2048 blocks --------
__global__ __launch_bounds__(256) void k_head(
    const float* __restrict__ sf, const float* __restrict__ qp,
    const float* __restrict__ sp, const int* __restrict__ idx,
    const unsigned short* __restrict__ Wf,    // fragment-major bf16 128x128
    const float* __restrict__ bias,           // b1
    unsigned short* __restrict__ hout,        // bf16 (BN,CH) pre-GN
    float* __restrict__ part_out)             // (MNBLK,16)
{
    // XCD swizzle: 2 XCDs per batch -> per-XCD gather working set = one batch
    const int rep = blockIdx.x & 7;
    const int q8  = blockIdx.x >> 3;                   // 0..255
    const int bi  = (rep >> 1) * MBPB + (rep & 1) * 256 + q8;
    const int b   = rep >> 1;
    const int t   = threadIdx.x;

    __shared__ unsigned short Xl[MRPB * XS];  // 4864 B
    __shared__ float wv[MRPB * KNB];          // 1024 B
    __shared__ float winv[MRPB];
    __shared__ float pw[4][4];

    // ---- IDW weights: one (row,k) pair per thread ----
    {
        int row = t >> 4, k = t & 15;
        size_t rg = (size_t)bi * MRPB + row;
        float qx = qp[rg * 3 + 0], qy = qp[rg * 3 + 1], qz = qp[rg * 3 + 2];
        const float* spp = sp + (rg * KNB + k) * 3;
        float dx = spp[0] - qx, dy = spp[1] - qy, dz = spp[2] - qz;
        wv[t] = 1.0f / (dx * dx + dy * dy + dz * dz + 1e-8f);
    }
    __syncthreads();
    if (t < MRPB) {
        float s = 0.f;
        #pragma unroll
        for (int k = 0; k < KNB; k++) s += wv[t * KNB + k];
        winv[t] = 1.0f / s;
    }
    __syncthreads();
    // ---- gather: 8 groups x 32 lanes, 2 rows each; 2 x 8-deep load batches ----
    {
        const int grp = t >> 5, c4 = (t & 31) * 4;
        const float* base = sf + (size_t)b * MS * CH + c4;
        for (int rr = 0; rr < 2; rr++) {
            int row = grp * 2 + rr;
            size_t rg = (size_t)bi * MRPB + row;
            const int4* ip4 = (const int4*)(idx + rg * KNB);
            const float4* wr4 = (const float4*)(wv + row * KNB);
            float4 w0 = wr4[0], w1 = wr4[1], w2 = wr4[2], w3 = wr4[3];
            // batch 1: 8 outstanding float4 loads
            int4 ia = ip4[0], ib = ip4[1];
            float4 f0 = *(const float4*)(base + (size_t)ia.x * CH);
            float4 f1 = *(const float4*)(base + (size_t)ia.y * CH);
            float4 f2 = *(const float4*)(base + (size_t)ia.z * CH);
            float4 f3 = *(const float4*)(base + (size_t)ia.w * CH);
            float4 f4 = *(const float4*)(base + (size_t)ib.x * CH);
            float4 f5 = *(const float4*)(base + (size_t)ib.y * CH);
            float4 f6 = *(const float4*)(base + (size_t)ib.z * CH);
            float4 f7 = *(const float4*)(base + (size_t)ib.w * CH);
            float ax, ay, az, aw;
            ax  = w0.x * f0.x;  ay  = w0.x * f0.y;  az  = w0.x * f0.z;  aw  = w0.x * f0.w;
            ax += w0.y * f1.x;  ay += w0.y * f1.y;  az += w0.y * f1.z;  aw += w0.y * f1.w;
            ax += w0.z * f2.x;  ay += w0.z * f2.y;  az += w0.z * f2.z;  aw += w0.z * f2.w;
            ax += w0.w * f3.x;  ay += w0.w * f3.y;  az += w0.w * f3.z;  aw += w0.w * f3.w;
            ax += w1.x * f4.x;  ay += w1.x * f4.y;  az += w1.x * f4.z;  aw += w1.x * f4.w;
            ax += w1.y * f5.x;  ay += w1.y * f5.y;  az += w1.y * f5.z;  aw += w1.y * f5.w;
            ax += w1.z * f6.x;  ay += w1.z * f6.y;  az += w1.z * f6.z;  aw += w1.z * f6.w;
            ax += w1.w * f7.x;  ay += w1.w * f7.y;  az += w1.w * f7.z;  aw += w1.w * f7.w;
            // batch 2: next 8 loads
            int4 ic = ip4[2], id = ip4[3];
            float4 f8  = *(const float4*)(base + (size_t)ic.x * CH);
            float4 f9  = *(const float4*)(base + (size_t)ic.y * CH);
            float4 f10 = *(const float4*)(base + (size_t)ic.z * CH);
            float4 f11 = *(const float4*)(base + (size_t)ic.w * CH);
            float4 f12 = *(const float4*)(base + (size_t)id.x * CH);
            float4 f13 = *(const float4*)(base + (size_t)id.y * CH);
            float4 f14 = *(const float4*)(base + (size_t)id.z * CH);
            float4 f15 = *(const float4*)(base + (size_t)id.w * CH);
            ax += w2.x * f8.x;  ay += w2.x * f8.y;  az += w2.x * f8.z;  aw += w2.x * f8.w;
            ax += w2.y * f9.x;  ay += w2.y * f9.y;  az += w2.y * f9.z;  aw += w2.y * f9.w;
            ax += w2.z * f10.x; ay += w2.z * f10.y; az += w2.z * f10.z; aw += w2.z * f10.w;
            ax += w2.w * f11.x; ay += w2.w * f11.y; az += w2.w * f11.z; aw += w2.w * f11.w;
            ax += w3.x * f12.x; ay += w3.x * f12.y; az += w3.x * f12.z; aw += w3.x * f12.w;
            ax += w3.y * f13.x; ay += w3.y * f13.y; az += w3.y * f13.z; aw += w3.y * f13.w;
            ax += w3.z * f14.x; ay += w3.z * f14.y; az += w3.z * f14.z; aw += w3.z * f14.w;
            ax += w3.w * f15.x; ay += w3.w * f15.y; az += w3.w * f15.z; aw += w3.w * f15.w;
            float wi = winv[row];
            ushort4 pk;
            pk.x = f2bs(ax * wi); pk.y = f2bs(ay * wi);
            pk.z = f2bs(az * wi); pk.w = f2bs(aw * wi);
            *(ushort4*)&Xl[row * XS + c4] = pk;
        }
    }
    __syncthreads();

    // ---- MFMA: wave w -> n-tiles {2w, 2w+1}, rows 0..15 (column-split) ----
    const int w  = t >> 6;
    const int l  = t & 63;
    const int lr = l & 15;
    const int qd = l >> 4;
    floatx4 acc2[2] = {};
    #pragma unroll
    for (int kt = 0; kt < 4; kt++) {
        short8 a = *(const short8*)&Xl[lr * XS + kt * 32 + qd * 8];
        #pragma unroll
        for (int jj = 0; jj < 2; jj++) {
            int j = w * 2 + jj;
            short8 bf = *(const short8*)(Wf + (((j * 4 + kt) * 64) + l) * 8);
            acc2[jj] = __builtin_amdgcn_mfma_f32_16x16x32_bf16(a, bf, acc2[jj], 0, 0, 0);
        }
    }

    // ---- epilogue: bias, group partials ----
    float vals[2][4];
    #pragma unroll
    for (int jj = 0; jj < 2; jj++) {
        int j = w * 2 + jj;
        float bj = bias[j * 16 + lr];
        float ss = 0.f, qq = 0.f;
        #pragma unroll
        for (int r = 0; r < 4; r++) {
            float v = acc2[jj][r] + bj;
            vals[jj][r] = v;
            ss += v; qq += v * v;
        }
        #pragma unroll
        for (int off = 32; off; off >>= 1) {
            ss += __shfl_down(ss, off);
            qq += __shfl_down(qq, off);
        }
        if (l == 0) { pw[w][jj] = ss; pw[w][2 + jj] = qq; }
    }
    __syncthreads();   // all waves done READING Xl (A frags shared) + pw ready

    // ---- scatter C into Xl (disjoint col ranges) + partials out ----
    #pragma unroll
    for (int jj = 0; jj < 2; jj++)
        #pragma unroll
        for (int r = 0; r < 4; r++)
            Xl[(qd * 4 + r) * XS + (w * 2 + jj) * 16 + lr] = f2bs(vals[jj][r]);
    if (t < 8)
        part_out[(size_t)bi * 16 + t] = pw[t >> 1][t & 1];
    else if (t < 16) {
        int g = t - 8;
        part_out[(size_t)bi * 16 + t] = pw[g >> 1][2 + (g & 1)];
    }
    __syncthreads();

    // ---- store h (coalesced) ----
    {
        int flat = t * 8;
        int row = flat >> 7, col = flat & 127;
        *(short8*)(hout + (size_t)bi * (MRPB * CH) + flat) =
            *(const short8*)&Xl[row * XS + col];
    }
}

// ---------------- mid: 16-row tile, 2048 blocks (round-10 proven) ----------------
template <int RESID>
__global__ __launch_bounds__(256) void k_mid(
    const unsigned short* __restrict__ hin,   // bf16 pre-GN h
    const float* __restrict__ part_in,        // (MNBLK,16), 512 rows/batch
    const float* __restrict__ gamma,          // prev layer GN
    const float* __restrict__ beta,
    const float* __restrict__ qf,             // residual f32 (RESID)
    const unsigned short* __restrict__ Wf,    // fragment-major bf16 128x128
    const float* __restrict__ bias,           // this layer's bias
    unsigned short* __restrict__ hout,        // bf16 (BN,CH) pre-GN
    float* __restrict__ part_out)             // (MNBLK,16)
{
    const int bi = blockIdx.x;                // 0..2047
    const int t  = threadIdx.x;
    const int b  = bi / MBPB;

    __shared__ unsigned short Xl[MRPB * XS];  // 4864 B
    __shared__ float red[16][17];
    __shared__ float2 stats_s[NG];
    __shared__ float pw[4][4];

    // ---- stats re-reduce (512 partial rows/batch) ----
    constexpr int R = 32;                     // 512 / 16
    {
        int j = t & 15, chunk = t >> 4;
        float acc = 0.f;
        #pragma unroll
        for (int i = 0; i < R; i++)
            acc += part_in[(size_t)(b * 512 + chunk * R + i) * 16 + j];
        red[chunk][j] = acc;
    }
    __syncthreads();
    if (t < NG) {
        float s = 0.f, q = 0.f;
        #pragma unroll
        for (int c = 0; c < 16; c++) { s += red[c][t]; q += red[c][t + 8]; }
        const float cnt = (float)(NPB * CG);
        float mean = s / cnt;
        float var  = q / cnt - mean * mean;
        stats_s[t] = make_float2(mean, rsqrtf(var + 1e-5f));
    }
    __syncthreads();

    // ---- GN + LeakyReLU (+resid) -> bf16 X tile ----
    {
        int flat = t * 8;
        int row = flat >> 7, col = flat & 127;
        size_t gidx = (size_t)bi * (MRPB * CH) + flat;
        short8 hv = *(const short8*)(hin + gidx);
        float2 st = stats_s[col >> 4];
        float4 g0 = *(const float4*)(gamma + col);
        float4 g1 = *(const float4*)(gamma + col + 4);
        float4 b0 = *(const float4*)(beta + col);
        float4 b1 = *(const float4*)(beta + col + 4);
        float gg[8] = {g0.x, g0.y, g0.z, g0.w, g1.x, g1.y, g1.z, g1.w};
        float bb[8] = {b0.x, b0.y, b0.z, b0.w, b1.x, b1.y, b1.z, b1.w};
        float re[8];
        if (RESID) {
            float4 r0 = *(const float4*)(qf + gidx);
            float4 r1 = *(const float4*)(qf + gidx + 4);
            re[0]=r0.x; re[1]=r0.y; re[2]=r0.z; re[3]=r0.w;
            re[4]=r1.x; re[5]=r1.y; re[6]=r1.z; re[7]=r1.w;
        }
        unsigned short ov[8];
        #pragma unroll
        for (int e = 0; e < 8; e++) {
            float v = bs2f((unsigned short)hv[e]);
            float y = (v - st.x) * st.y * gg[e] + bb[e];
            y = (y >= 0.f) ? y : 0.1f * y;
            if (RESID) y += re[e];
            ov[e] = f2bs(y);
        }
        *(short8*)&Xl[row * XS + col] = *(short8*)ov;
    }
    __syncthreads();

    // ---- MFMA: wave w -> n-tiles {2w, 2w+1}, rows 0..15 ----
    const int w  = t >> 6;
    const int l  = t & 63;
    const int lr = l & 15;
    const int qd = l >> 4;
    floatx4 acc2[2] = {};
    #pragma unroll
    for (int kt = 0; kt < 4; kt++) {
        short8 a = *(const short8*)&Xl[lr * XS + kt * 32 + qd * 8];
        #pragma unroll
        for (int jj = 0; jj < 2; jj++) {
            int j = w * 2 + jj;
            short8 bf = *(const short8*)(Wf + (((j * 4 + kt) * 64) + l) * 8);
            acc2[jj] = __builtin_amdgcn_mfma_f32_16x16x32_bf16(a, bf, acc2[jj], 0, 0, 0);
        }
    }

    // ---- epilogue: bias, group partials ----
    float vals[2][4];
    #pragma unroll
    for (int jj = 0; jj < 2; jj++) {
        int j = w * 2 + jj;
        float bj = bias[j * 16 + lr];
        float ss = 0.f, qq = 0.f;
        #pragma unroll
        for (int r = 0; r < 4; r++) {
            float v = acc2[jj][r] + bj;
            vals[jj][r] = v;
            ss += v; qq += v * v;
        }
        #pragma unroll
        for (int off = 32; off; off >>= 1) {
            ss += __shfl_down(ss, off);
            qq += __shfl_down(qq, off);
        }
        if (l == 0) { pw[w][jj] = ss; pw[w][2 + jj] = qq; }
    }
    __syncthreads();   // all waves done READING Xl (A frags shared) + pw ready

    // ---- scatter C into Xl (disjoint col ranges) + partials out ----
    #pragma unroll
    for (int jj = 0; jj < 2; jj++)
        #pragma unroll
        for (int r = 0; r < 4; r++)
            Xl[(qd * 4 + r) * XS + (w * 2 + jj) * 16 + lr] = f2bs(vals[jj][r]);
    if (t < 8)
        part_out[(size_t)bi * 16 + t] = pw[t >> 1][t & 1];
    else if (t < 16) {
        int g = t - 8;
        part_out[(size_t)bi * 16 + t] = pw[g >> 1][2 + (g & 1)];
    }
    __syncthreads();

    // ---- store h (coalesced) ----
    {
        int flat = t * 8;
        int row = flat >> 7, col = flat & 127;
        *(short8*)(hout + (size_t)bi * (MRPB * CH) + flat) =
            *(const short8*)&Xl[row * XS + col];
    }
}

// ---------------- final GN + LeakyReLU -> f32 out (16-row tiles) ----------------
__global__ __launch_bounds__(256) void k_out(
    const unsigned short* __restrict__ hin, const float* __restrict__ part_in,
    const float* __restrict__ gamma, const float* __restrict__ beta,
    float* __restrict__ out)
{
    const int bi = blockIdx.x;                // 0..2047
    const int t  = threadIdx.x;
    const int b  = bi / MBPB;
    __shared__ float red[16][17];
    __shared__ float2 stats_s[NG];
    constexpr int R = 32;                     // 512 partial rows/batch
    {
        int j = t & 15, chunk = t >> 4;
        float acc = 0.f;
        #pragma unroll
        for (int i = 0; i < R; i++)
            acc += part_in[(size_t)(b * 512 + chunk * R + i) * 16 + j];
        red[chunk][j] = acc;
    }
    __syncthreads();
    if (t < NG) {
        float s = 0.f, q = 0.f;
        #pragma unroll
        for (int c = 0; c < 16; c++) { s += red[c][t]; q += red[c][t + 8]; }
        const float cnt = (float)(NPB * CG);
        float mean = s / cnt;
        float var  = q / cnt - mean * mean;
        stats_s[t] = make_float2(mean, rsqrtf(var + 1e-5f));
    }
    __syncthreads();
    {
        int flat = t * 8;
        int col = flat & 127;
        size_t gidx = (size_t)bi * (MRPB * CH) + flat;
        short8 hv = *(const short8*)(hin + gidx);
        float2 st = stats_s[col >> 4];
        float4 g0 = *(const float4*)(gamma + col);
        float4 g1 = *(const float4*)(gamma + col + 4);
        float4 b0 = *(const float4*)(beta + col);
        float4 b1 = *(const float4*)(beta + col + 4);
        float gg[8] = {g0.x, g0.y, g0.z, g0.w, g1.x, g1.y, g1.z, g1.w};
        float bb[8] = {b0.x, b0.y, b0.z, b0.w, b1.x, b1.y, b1.z, b1.w};
        float o[8];
        #pragma unroll
        for (int e = 0; e < 8; e++) {
            float v = bs2f((unsigned short)hv[e]);
            float y = (v - st.x) * st.y * gg[e] + bb[e];
            o[e] = (y >= 0.f) ? y : 0.1f * y;
        }
        float4 o0 = {o[0], o[1], o[2], o[3]};
        float4 o1 = {o[4], o[5], o[6], o[7]};
        *(float4*)(out + gidx)     = o0;
        *(float4*)(out + gidx + 4) = o1;
    }
}

extern "C" void kernel_launch(void* const* d_in, const int* in_sizes, int n_in,
                              void* d_out, int out_size, void* d_ws, size_t ws_size,
                              hipStream_t stream) {
    const float* qf  = (const float*)d_in[0];
    const float* sf  = (const float*)d_in[1];
    const float* qp  = (const float*)d_in[2];
    const float* sp  = (const float*)d_in[3];
    const int*   idx = (const int*)  d_in[4];
    const float* W1  = (const float*)d_in[5];
    const float* b1  = (const float*)d_in[6];
    const float* g1  = (const float*)d_in[7];
    const float* be1 = (const float*)d_in[8];
    const float* W2  = (const float*)d_in[9];
    const float* b2  = (const float*)d_in[10];
    const float* g2  = (const float*)d_in[11];
    const float* be2 = (const float*)d_in[12];
    const float* W3  = (const float*)d_in[13];
    const float* b3  = (const float*)d_in[14];
    const float* g3  = (const float*)d_in[15];
    const float* be3 = (const float*)d_in[16];

    char* ws = (char*)d_ws;
    unsigned short* Wf1 = (unsigned short*)(ws);
    unsigned short* Wf2 = (unsigned short*)(ws + 32768);
    unsigned short* Wf3 = (unsigned short*)(ws + 65536);
    float* p1 = (float*)(ws + 98304);                    // 2048*16*4 = 128 KB
    float* p2 = (float*)(ws + 229376);                   // 128 KB
    float* p3 = (float*)(ws + 360448);                   // 128 KB
    unsigned short* h1 = (unsigned short*)(ws + 524288);             // 8 MB
    unsigned short* h2 = (unsigned short*)(ws + 524288 + 8388608);   // 8 MB
    unsigned short* h3 = (unsigned short*)(ws + 524288 + 2 * 8388608);
    float* out = (float*)d_out;

    k_prep<<<192, 256, 0, stream>>>(W1, W2, W3, Wf1, Wf2, Wf3);
    k_head<<<MNBLK, 256, 0, stream>>>(sf, qp, sp, idx, Wf1, b1, h1, p1);
    k_mid<0><<<MNBLK, 256, 0, stream>>>(h1, p1, g1, be1, nullptr, Wf2, b2, h2, p2);
    k_mid<1><<<MNBLK, 256, 0, stream>>>(h2, p2, g2, be2, qf, Wf3, b3, h3, p3);
    k_out<<<MNBLK, 256, 0, stream>>>(h3, p3, g3, be3, out);
}